// Round 1
// baseline (839.481 us; speedup 1.0000x reference)
//
#include <hip/hip_runtime.h>
#include <math.h>

#define EPSN 1e-12f
#define EPSS 1e-8f

__device__ __forceinline__ float wred_sum(float v) {
#pragma unroll
    for (int o = 32; o > 0; o >>= 1) v += __shfl_down(v, o, 64);
    return v;
}
__device__ __forceinline__ float wred_max(float v) {
#pragma unroll
    for (int o = 32; o > 0; o >>= 1) v = fmaxf(v, __shfl_down(v, o, 64));
    return v;
}

// block reduction (blockDim.x multiple of 64, <=256) with broadcast to all threads
__device__ __forceinline__ float bred_sum(float v, float* red) {
    const int lane = threadIdx.x & 63;
    const int w = threadIdx.x >> 6;
    const int nw = blockDim.x >> 6;
    v = wred_sum(v);
    __syncthreads();              // protect red from previous use
    if (lane == 0) red[w] = v;
    __syncthreads();
    float r = red[0];
    for (int i = 1; i < nw; ++i) r += red[i];
    return r;
}
__device__ __forceinline__ float bred_max(float v, float* red) {
    const int lane = threadIdx.x & 63;
    const int w = threadIdx.x >> 6;
    const int nw = blockDim.x >> 6;
    v = wred_max(v);
    __syncthreads();
    if (lane == 0) red[w] = v;
    __syncthreads();
    float r = red[0];
    for (int i = 1; i < nw; ++i) r = fmaxf(r, red[i]);
    return r;
}

// Kernel A: per-batch normalized query vector + clamped index
__global__ __launch_bounds__(256)
void k_prep(const float* __restrict__ reps, const int* __restrict__ qrels,
            float* __restrict__ qn, int* __restrict__ qidx, int R, int D) {
    __shared__ float red[4];
    const int b = blockIdx.x;
    const int tid = threadIdx.x;
    int q = qrels[b];
    q = q < 0 ? 0 : (q >= R ? R - 1 : q);
    const size_t base = ((size_t)b * R + q) * D;
    float v = (tid < D) ? reps[base + tid] : 0.f;
    float ss = bred_sum(v * v, red);
    float n = fmaxf(sqrtf(ss), EPSN);
    if (tid < D) qn[(size_t)b * D + tid] = v / n;
    if (tid == 0) qidx[b] = q;
}

// Kernel B: fused copy reps->out + cosine sims. One wave per row (D=256 -> 64 lanes x float4).
__global__ __launch_bounds__(256)
void k_copy_sims(const float* __restrict__ reps, const float* __restrict__ qn,
                 float* __restrict__ out, float* __restrict__ sims,
                 int R, int Dq /* D/4 */, int nrows) {
    const int lane = threadIdx.x & 63;
    const int wid = threadIdx.x >> 6;
    const int row = blockIdx.x * (blockDim.x >> 6) + wid;
    if (row >= nrows) return;
    const unsigned b = (unsigned)row / (unsigned)R;
    const float4* __restrict__ src = (const float4*)reps + (size_t)row * Dq;
    float4* __restrict__ dst = (float4*)out + (size_t)row * Dq;
    const float4* __restrict__ qv = (const float4*)qn + (size_t)b * Dq;
    float dot = 0.f, ss = 0.f;
    for (int i = lane; i < Dq; i += 64) {
        float4 v = src[i];
        dst[i] = v;
        float4 qq = qv[i];                       // tiny, L1/L2-resident
        dot += v.x * qq.x + v.y * qq.y + v.z * qq.z + v.w * qq.w;
        ss  += v.x * v.x + v.y * v.y + v.z * v.z + v.w * v.w;
    }
    dot = wred_sum(dot);
    ss  = wred_sum(ss);
    if (lane == 0) sims[row] = dot / fmaxf(sqrtf(ss), EPSN);
}

// Kernel C: per-batch masked softmax weighting; overwrite out[b, q, :].
// Assumes R <= 8192 (LDS sims buffer), D == blockDim.x == 256.
__global__ __launch_bounds__(256)
void k_epilogue(const float* __restrict__ reps, const float* __restrict__ sims_g,
                const int* __restrict__ qidx,
                const float* __restrict__ p_thr, const float* __restrict__ p_str,
                const float* __restrict__ p_scale, const float* __restrict__ p_temp,
                float* __restrict__ out, int R, int D) {
    __shared__ float s_sims[8192];
    __shared__ float s_w[2048];
    __shared__ int   s_r[2048];
    __shared__ float red[4];
    __shared__ int   s_cnt;

    const int b = blockIdx.x;
    const int tid = threadIdx.x;
    const int T = blockDim.x;
    const int q = qidx[b];

    const float threshold = 1.f / (1.f + expf(-p_thr[0]));
    const float strength  = 0.2f / (1.f + expf(-p_str[0]));
    const float scale     = p_scale[0];
    float temp = p_temp[0];
    temp = fminf(fmaxf(temp, 0.1f), 10.f);
    const float invT = 1.f / temp;

    // pass 1: load sims, self-exclude, max of masked
    const float* srow = sims_g + (size_t)b * R;
    float lmax = -INFINITY;
    for (int r = tid; r < R; r += T) {
        float s = srow[r];
        if (r == q) s = -1.f;
        s_sims[r] = s;
        if (s > threshold) lmax = fmaxf(lmax, s);
    }
    const float smax = bred_max(lmax, red);
    const bool has_valid = (smax > -INFINITY);
    const float m = smax * invT;   // max logit (invT > 0)

    // pass 2: softmax denominator over masked (unmasked exp(-1e30-m) underflows to 0 in ref)
    float lz = 0.f;
    for (int r = tid; r < R; r += T) {
        float s = s_sims[r];
        if (s > threshold) lz += expf(s * invT - m);
    }
    const float Z = bred_sum(lz, red);
    const float invZ = has_valid ? (1.f / Z) : 0.f;

    // pass 3: sum of adjusted
    float lS = 0.f;
    for (int r = tid; r < R; r += T) {
        float s = s_sims[r];
        if (s > threshold) {
            float a = expf(s * invT - m) * invZ
                    * (1.f / (1.f + expf(-(s - threshold) * 10.f)))
                    * (1.f + scale * s);
            lS += a;
        }
    }
    const float S = bred_sum(lS, red);
    const float invS = 1.f / (S + EPSS);

    // pass 4: chunked compaction + weighted row accumulation (thread tid owns dim d=tid)
    float acc = 0.f;
    for (int base = 0; base < R; base += 2048) {
        if (tid == 0) s_cnt = 0;
        __syncthreads();
        int lim = base + 2048; if (lim > R) lim = R;
        for (int r = base + tid; r < lim; r += T) {
            float s = s_sims[r];
            if (s > threshold) {
                float a = expf(s * invT - m) * invZ
                        * (1.f / (1.f + expf(-(s - threshold) * 10.f)))
                        * (1.f + scale * s) * invS;
                int j = atomicAdd(&s_cnt, 1);
                s_r[j] = r;
                s_w[j] = a;
            }
        }
        __syncthreads();
        const int cnt = s_cnt;
        for (int j = 0; j < cnt; ++j)
            acc += s_w[j] * reps[((size_t)b * R + s_r[j]) * D + tid];
        __syncthreads();
    }

    if (tid < D) {
        const size_t o = ((size_t)b * R + q) * D + tid;
        const float qv = reps[o];
        out[o] = has_valid ? ((1.f - strength) * qv + strength * acc) : qv;
    }
}

extern "C" void kernel_launch(void* const* d_in, const int* in_sizes, int n_in,
                              void* d_out, int out_size, void* d_ws, size_t ws_size,
                              hipStream_t stream) {
    const float* reps   = (const float*)d_in[0];
    const int*   qrels  = (const int*)d_in[1];
    const float* p_thr  = (const float*)d_in[2];
    const float* p_str  = (const float*)d_in[3];
    const float* p_scale= (const float*)d_in[4];
    const float* p_temp = (const float*)d_in[5];
    float* out = (float*)d_out;

    const int D = 256;
    const int R = 8192;
    const int B = (int)(in_sizes[0] / ((long long)R * D));   // 64

    // workspace layout: sims [B*R] f32 | qn [B*D] f32 | qidx [B] i32
    float* ws_sims = (float*)d_ws;
    float* ws_qn   = ws_sims + (size_t)B * R;
    int*   ws_q    = (int*)(ws_qn + (size_t)B * D);

    k_prep<<<B, 256, 0, stream>>>(reps, qrels, ws_qn, ws_q, R, D);

    const int nrows = B * R;                 // 524288 rows, one wave each
    const int wpb = 256 / 64;                // 4 waves/block
    const int blocks = (nrows + wpb - 1) / wpb;
    k_copy_sims<<<blocks, 256, 0, stream>>>(reps, ws_qn, out, ws_sims, R, D / 4, nrows);

    k_epilogue<<<B, 256, 0, stream>>>(reps, ws_sims, ws_q, p_thr, p_str, p_scale, p_temp,
                                      out, R, D);
}